// Round 14
// baseline (141.744 us; speedup 1.0000x reference)
//
#include <hip/hip_runtime.h>

// ActivatedAttention: out = transpose(GroupNorm( relu(rope(Q)) @ [relu(rope(K))^T @ relu(V)] )).
// B=4, T=2048, D=1024. y = Q @ (K^T V)  (no softmax -> associativity).
// All GEMMs hi-only bf16 (absmax 0.0234 vs threshold 0.0728, bench-validated).
//  - gemm1f: r10 exact (bf16 xh staged via global_load_lds; r12 lesson: in-kernel f32
//    A staging thrashes L2). 128x128, 4 waves, BK=64, dbuf, counted vmcnt(8).
//  - gemm2: r12 64x128 tile, 512 blocks.
//  - gemm3g (NEW r14): ported to gemm2's 64x128 tile / wave=64mx32n / 1024 blocks /
//    48KB LDS. Each wave's 32 n-cols = exactly one GroupNorm group -> same shfl reduce.
// Barrier skeleton (r7-proven): vmcnt(N); s_barrier; sched_barrier; ds_reads;
// lgkmcnt(0); sched_barrier; s_barrier; MFMAs.
// r11: BK=32 doubles per-sync overhead. r9: 32x32 MFMA frags bank-conflict on 128B rows.
// Staging swizzle: linear LDS dest, XOR-swizzled global source + swizzled ds_read
// (slot ^= row&7 on [rows][64] bf16 buffers) -> conflict-free.

typedef unsigned short u16;
typedef __attribute__((ext_vector_type(8))) unsigned short u16x8;
typedef __attribute__((ext_vector_type(4))) float fx4;
typedef __attribute__((ext_vector_type(8))) __bf16 bfx8;

#define TP 129  // epilogue f32 tile pitch

__device__ __forceinline__ u16 f2bh(float v) {  // f32 -> bf16 RNE
  unsigned u = __float_as_uint(v);
  return (u16)((u + 0x7FFFu + ((u >> 16) & 1u)) >> 16);
}
__device__ __forceinline__ fx4 mfma16(bfx8 a, bfx8 b, fx4 c) {
  return __builtin_amdgcn_mfma_f32_16x16x32_bf16(a, b, c, 0, 0, 0);
}

__device__ __forceinline__ void gload16(const u16* g, u16* l) {
  __builtin_amdgcn_global_load_lds(
      (const __attribute__((address_space(1))) unsigned int*)(const void*)g,
      (__attribute__((address_space(3))) unsigned int*)(void*)l, 16, 0, 0);
}

// Swizzled LDS read: buffer is [rows][8 slots of 16B]; logical slot q of row r
// lives at physical slot q ^ (r&7).
__device__ __forceinline__ bfx8 ldsw(const u16* lds, int row, int slot) {
  const char* p = (const char*)lds + row * 128 + ((slot ^ (row & 7)) << 4);
  return __builtin_bit_cast(bfx8, *reinterpret_cast<const u16x8*>(p));
}

// Stage 128 rows x 64 cols (4 chunks/thread) via global_load_lds.
__device__ __forceinline__ void stage4(const u16* __restrict__ A,
                                       size_t rowBase, int stride, int k0,
                                       u16* lds, int w, int lane) {
#pragma unroll
  for (int i = 0; i < 4; ++i) {
    int c = ((w * 4 + i) << 6) + lane;
    int r = c >> 3, s = c & 7;
    int t = s ^ (r & 7);
    const u16* src = A + (rowBase + (size_t)r) * (size_t)stride + k0 + (t << 3);
    gload16(src, lds + ((w * 4 + i) << 9));
  }
}

// Stage 64 rows x 64 cols (2 chunks/thread) via global_load_lds.
__device__ __forceinline__ void stageA2(const u16* __restrict__ A,
                                        size_t rowBase, int stride, int k0,
                                        u16* lds, int w, int lane) {
#pragma unroll
  for (int i = 0; i < 2; ++i) {
    int c = ((w * 2 + i) << 6) + lane;  // 0..511
    int r = c >> 3, s = c & 7;
    int t = s ^ (r & 7);
    const u16* src = A + (rowBase + (size_t)r) * (size_t)stride + k0 + (t << 3);
    gload16(src, lds + ((w * 2 + i) << 9));
  }
}

// ---- Pipelined hi-only 128x128 GEMM core, BK=64, dbuf staging (r10-proven).
__device__ inline void gemm_core_pipe(const u16* __restrict__ A, size_t aBase, int aStr,
                                      const u16* __restrict__ B, size_t bBase, int bStr, int K,
                                      u16* sA0, u16* sB0, u16* sA1, u16* sB1,
                                      fx4 acc[4][4], int w, int lane) {
  int wm = (w >> 1) * 64, wn = (w & 1) * 64;
  int lr = lane & 15, lk = lane >> 4;
  stage4(A, aBase, aStr, 0, sA0, w, lane);
  stage4(B, bBase, bStr, 0, sB0, w, lane);
  int NT = K >> 6;
  for (int t = 0; t < NT; ++t) {
    u16* cA = (t & 1) ? sA1 : sA0;
    u16* cB = (t & 1) ? sB1 : sB0;
    if (t + 1 < NT) {
      u16* nA = (t & 1) ? sA0 : sA1;
      u16* nB = (t & 1) ? sB0 : sB1;
      stage4(A, aBase, aStr, (t + 1) << 6, nA, w, lane);
      stage4(B, bBase, bStr, (t + 1) << 6, nB, w, lane);
      asm volatile("s_waitcnt vmcnt(8)" ::: "memory");  // tile-t loads done, 8 in flight
    } else {
      asm volatile("s_waitcnt vmcnt(0)" ::: "memory");
    }
    __builtin_amdgcn_s_barrier();       // tile t resident (all waves)
    __builtin_amdgcn_sched_barrier(0);  // do NOT hoist reads above the barrier (race!)
    bfx8 a[8], b[8];
#pragma unroll
    for (int h = 0; h < 2; ++h)
#pragma unroll
      for (int i = 0; i < 4; ++i) {
        a[h * 4 + i] = ldsw(cA, wm + i * 16 + lr, h * 4 + lk);
        b[h * 4 + i] = ldsw(cB, wn + i * 16 + lr, h * 4 + lk);
      }
    asm volatile("s_waitcnt lgkmcnt(0)" ::: "memory");  // reads landed in regs
    __builtin_amdgcn_sched_barrier(0);
    __builtin_amdgcn_s_barrier();       // WAR: buffers free; MFMAs overlap next staging
#pragma unroll
    for (int h = 0; h < 2; ++h)
#pragma unroll
      for (int mi = 0; mi < 4; ++mi)
#pragma unroll
        for (int ni = 0; ni < 4; ++ni)
          acc[mi][ni] = mfma16(a[h * 4 + mi], b[h * 4 + ni], acc[mi][ni]);
  }
}

// ---- K0: merged prep: castX (blocks 0..4095), transW (4096..7167), ropetab (7168..15359)
__global__ void k_prep(const float* __restrict__ x, const float* __restrict__ W,
                       u16* __restrict__ xh, u16* __restrict__ WTh,
                       float2* __restrict__ tabTI, float2* __restrict__ tabIT) {
  __shared__ float tile[32][33];
  int bid = blockIdx.x, tid = threadIdx.x;
  if (bid < 4096) {  // cast x -> bf16, 8 elems/thread
    size_t i = ((size_t)bid * 256 + tid) * 8;
    fx4 v0 = *reinterpret_cast<const fx4*>(x + i);
    fx4 v1 = *reinterpret_cast<const fx4*>(x + i + 4);
    u16x8 h;
#pragma unroll
    for (int j = 0; j < 4; ++j) {
      h[j] = f2bh(v0[j]);
      h[4 + j] = f2bh(v1[j]);
    }
    *reinterpret_cast<u16x8*>(xh + i) = h;
  } else if (bid < 7168) {  // transpose W -> WT[3072][1024] bf16
    int idx = bid - 4096;
    int n0 = (idx % 96) * 32, k0 = (idx / 96) * 32;
    int c = tid & 31, r4 = tid >> 5;
#pragma unroll
    for (int it = 0; it < 4; ++it) {
      int r = r4 + it * 8;
      tile[r][c] = W[(size_t)(k0 + r) * 3072 + n0 + c];
    }
    __syncthreads();
#pragma unroll
    for (int it = 0; it < 4; ++it) {
      int r = r4 + it * 8;
      WTh[(size_t)(n0 + r) * 1024 + k0 + c] = f2bh(tile[c][r]);
    }
  } else {  // rope tables: float2(cos,sin)
    int half = (bid - 7168) >> 12;  // 0: tabTI, 1: tabIT
    int idx = ((bid - 7168) & 4095) * 256 + tid;
    int t, i;
    if (half == 0) {
      t = idx >> 9;
      i = idx & 511;
    } else {
      i = idx >> 11;
      t = idx & 2047;
    }
    float invf = exp2f(-(float)i * (13.287712379549449f / 512.f));  // 10000^(-i/512)
    float ang = (float)t * invf, s, c;
    sincosf(ang, &s, &c);
    if (half == 0)
      tabTI[idx] = make_float2(c, s);
    else
      tabIT[idx] = make_float2(c, s);
  }
}

// ---- G1 fused: relu(rope(x@W+b)) -> Qh row-major, Kth/Vth transposed [B][D][T]
__global__ __launch_bounds__(256) void k_gemm1f(const u16* __restrict__ xh,
                                                const u16* __restrict__ WTh,
                                                const float* __restrict__ b_in,
                                                const float2* __restrict__ tabTI,
                                                const float2* __restrict__ tabIT,
                                                u16* __restrict__ Qh, u16* __restrict__ Kth,
                                                u16* __restrict__ Vth) {
  __shared__ __align__(16) float shbuf[128 * TP];  // 66KB; 4x16KB staging buffers alias it
  u16* sA0 = (u16*)shbuf;
  u16* sB0 = sA0 + 128 * 64;
  u16* sA1 = sB0 + 128 * 64;
  u16* sB1 = sA1 + 128 * 64;
  // XCD-chunked swizzle: 1536 blocks = 8 XCD x (8 mt x 24 nt), mt-fastest within chunk.
  int bid = blockIdx.x;
  int xcd = bid & 7, idx = bid >> 3;
  int mt = (xcd << 3) + (idx & 7), nt = idx >> 3;
  int m0 = mt << 7, n0 = nt << 7;
  int tid = threadIdx.x, lane = tid & 63, w = tid >> 6;
  int wm = (w >> 1) * 64, wn = (w & 1) * 64;
  int lr = lane & 15, lk = lane >> 4;
  fx4 acc[4][4];
#pragma unroll
  for (int i = 0; i < 4; ++i)
#pragma unroll
    for (int j = 0; j < 4; ++j) acc[i][j] = fx4{0.f, 0.f, 0.f, 0.f};

  gemm_core_pipe(xh, (size_t)m0, 1024, WTh, (size_t)n0, 1024, 1024,
                 sA0, sB0, sA1, sB1, acc, w, lane);

  // ---- Epilogue: acc+bias -> f32 LDS tile [n_local][m_local], then store in output
  // order with vectorized u16x8 stores + table-based rope.
  float bv[4];
#pragma unroll
  for (int ni = 0; ni < 4; ++ni) bv[ni] = b_in[n0 + wn + ni * 16 + lr];
  __syncthreads();  // all LDS reads of staging done before overwrite
#pragma unroll
  for (int mi = 0; mi < 4; ++mi)
#pragma unroll
    for (int ni = 0; ni < 4; ++ni)
#pragma unroll
      for (int r = 0; r < 4; ++r)
        shbuf[(wn + ni * 16 + lr) * TP + wm + mi * 16 + lk * 4 + r] = acc[mi][ni][r] + bv[ni];
  __syncthreads();

  int part = n0 >> 10;       // 0=Q, 1=K, 2=V (uniform per block)
  int d0 = n0 - (part << 10);
  int bb = m0 >> 11, tb = m0 & 2047;  // 128-row tiles never cross batch boundary
  int rl0 = tid >> 4;        // row within tile (per pass: +16)
  int cc = (tid & 15) * 8;   // 8-elem column chunk

  if (part == 2) {           // V: relu only, store [d][t]
#pragma unroll
    for (int pass = 0; pass < 8; ++pass) {
      int rl = rl0 + pass * 16;
      u16x8 o;
#pragma unroll
      for (int j = 0; j < 8; ++j) o[j] = f2bh(fmaxf(shbuf[rl * TP + cc + j], 0.f));
      *reinterpret_cast<u16x8*>(Vth + (((size_t)(bb << 10) + d0 + rl) << 11) + tb + cc) = o;
    }
  } else if (part == 1) {    // K: rope (rows d, d^1) + relu, store [d][t]
#pragma unroll
    for (int pass = 0; pass < 8; ++pass) {
      int rl = rl0 + pass * 16;
      int d = d0 + rl;
      const float2* tp = tabIT + ((size_t)(d >> 1) << 11) + tb + cc;
      const float* e = shbuf + (rl & ~1) * TP + cc;   // even row
      const float* oo = shbuf + (rl | 1) * TP + cc;   // odd row
      int isOdd = d & 1;
      u16x8 o;
#pragma unroll
      for (int j = 0; j < 8; ++j) {
        float2 cs = tp[j];
        float x1 = e[j], x2 = oo[j];
        float v = isOdd ? (x1 * cs.y + x2 * cs.x) : (x1 * cs.x - x2 * cs.y);
        o[j] = f2bh(fmaxf(v, 0.f));
      }
      *reinterpret_cast<u16x8*>(Kth + (((size_t)(bb << 10) + d) << 11) + tb + cc) = o;
    }
  } else {                   // Q: rope along d, store [m][d]
#pragma unroll
    for (int pass = 0; pass < 8; ++pass) {
      int rl = rl0 + pass * 16;  // m_local
      int m = m0 + rl, t = m & 2047;
      const float2* tp = tabTI + ((size_t)t << 9) + ((d0 + cc) >> 1);
      u16x8 o;
#pragma unroll
      for (int jp = 0; jp < 4; ++jp) {
        float x1 = shbuf[(cc + 2 * jp) * TP + rl];
        float x2 = shbuf[(cc + 2 * jp + 1) * TP + rl];
        float2 cs = tp[jp];
        o[2 * jp] = f2bh(fmaxf(x1 * cs.x - x2 * cs.y, 0.f));
        o[2 * jp + 1] = f2bh(fmaxf(x1 * cs.y + x2 * cs.x, 0.f));
      }
      *reinterpret_cast<u16x8*>(Qh + ((size_t)m << 10) + d0 + cc) = o;
    }
  }
}

// ---- G2: KtVT[b][n][m] = (K^T V)[m][n], bf16 out. 64x128 tile, 512 blocks (r12-proven).
__global__ __launch_bounds__(256) void k_gemm2(const u16* __restrict__ Kth, const u16* __restrict__ Vth,
                                               u16* __restrict__ KtVTh) {
  __shared__ u16 smem[2 * (64 + 128) * 64];  // 48KB
  u16* sA0 = smem;
  u16* sB0 = sA0 + 64 * 64;
  u16* sA1 = sB0 + 128 * 64;
  u16* sB1 = sA1 + 64 * 64;
  fx4 acc[4][2];
#pragma unroll
  for (int i = 0; i < 4; ++i)
#pragma unroll
    for (int j = 0; j < 2; ++j) acc[i][j] = fx4{0.f, 0.f, 0.f, 0.f};
  // XCD swizzle: xcd owns (b = xcd>>1, 8 mt x 8 nt), mt-fastest -> A slice 2MB resident.
  int bid = blockIdx.x;
  int xcd = bid & 7, idx = bid >> 3;  // idx 0..63
  int b = xcd >> 1;
  int mt = (xcd & 1) * 8 + (idx & 7), nt = idx >> 3;
  int m0 = mt << 6, n0 = nt << 7;
  int tid = threadIdx.x, lane = tid & 63, w = tid >> 6;
  int wn2 = w * 32;  // wave owns 32 n-cols; full 64 m-rows
  int lr = lane & 15, lk = lane >> 4;
  const u16* Ab = Kth + ((size_t)b << 21);
  const u16* Bb = Vth + ((size_t)b << 21);

  stageA2(Ab, (size_t)m0, 2048, 0, sA0, w, lane);
  stage4(Bb, (size_t)n0, 2048, 0, sB0, w, lane);
  const int NT = 32;  // K=2048
  for (int t = 0; t < NT; ++t) {
    u16* cA = (t & 1) ? sA1 : sA0;
    u16* cB = (t & 1) ? sB1 : sB0;
    if (t + 1 < NT) {
      u16* nA = (t & 1) ? sA0 : sA1;
      u16* nB = (t & 1) ? sB0 : sB1;
      stageA2(Ab, (size_t)m0, 2048, (t + 1) << 6, nA, w, lane);
      stage4(Bb, (size_t)n0, 2048, (t + 1) << 6, nB, w, lane);
      asm volatile("s_waitcnt vmcnt(6)" ::: "memory");
    } else {
      asm volatile("s_waitcnt vmcnt(0)" ::: "memory");
    }
    __builtin_amdgcn_s_barrier();
    __builtin_amdgcn_sched_barrier(0);
    bfx8 a[8], bfr[4];
#pragma unroll
    for (int h = 0; h < 2; ++h) {
#pragma unroll
      for (int i = 0; i < 4; ++i) a[h * 4 + i] = ldsw(cA, i * 16 + lr, h * 4 + lk);
#pragma unroll
      for (int j = 0; j < 2; ++j) bfr[h * 2 + j] = ldsw(cB, wn2 + j * 16 + lr, h * 4 + lk);
    }
    asm volatile("s_waitcnt lgkmcnt(0)" ::: "memory");
    __builtin_amdgcn_sched_barrier(0);
    __builtin_amdgcn_s_barrier();
#pragma unroll
    for (int h = 0; h < 2; ++h)
#pragma unroll
      for (int mi = 0; mi < 4; ++mi)
#pragma unroll
        for (int ni = 0; ni < 2; ++ni)
          acc[mi][ni] = mfma16(a[h * 4 + mi], bfr[h * 2 + ni], acc[mi][ni]);
  }
#pragma unroll
  for (int mi = 0; mi < 4; ++mi)
#pragma unroll
    for (int ni = 0; ni < 2; ++ni)
#pragma unroll
      for (int r = 0; r < 4; ++r) {
        int m = m0 + mi * 16 + lk * 4 + r;
        int n = n0 + wn2 + ni * 16 + lr;
        KtVTh[((size_t)b << 20) + ((size_t)n << 10) + m] = f2bh(acc[mi][ni][r]);
      }
}

// ---- G3 fused (r14): y = Q @ KtV + GroupNorm + transposed store, on gemm2's proven
// 64x128 tile / wave=64m x 32n / 1024 blocks / 48KB LDS. Each wave's 32 n-cols are
// exactly one GN group (n0,wn2 32-aligned) -> same shfl_xor(1,2,4,8) reduce as r13.
__global__ __launch_bounds__(256) void k_gemm3g(const u16* __restrict__ Qh, const u16* __restrict__ KtVTh,
                                                const float* __restrict__ gw, const float* __restrict__ gb,
                                                float* __restrict__ out) {
  __shared__ u16 smem[2 * (64 + 128) * 64];  // 48KB
  u16* sA0 = smem;
  u16* sB0 = sA0 + 64 * 64;
  u16* sA1 = sB0 + 128 * 64;
  u16* sB1 = sA1 + 64 * 64;
  fx4 acc[4][2];
#pragma unroll
  for (int i = 0; i < 4; ++i)
#pragma unroll
    for (int j = 0; j < 2; ++j) acc[i][j] = fx4{0.f, 0.f, 0.f, 0.f};
  // 1024 blocks = 8 XCD x 128; xcd owns (b = xcd>>1, 16 mt x 8 nt), mt-fastest
  // -> A slice 16x64 rows x 2KB = 2MB L2-resident.
  int bid = blockIdx.x;
  int xcd = bid & 7, idx = bid >> 3;  // idx 0..127
  int b = xcd >> 1;
  int mt = (xcd & 1) * 16 + (idx & 15), nt = idx >> 4;  // mt 0..31, nt 0..7
  int m0 = mt << 6, n0 = nt << 7;
  int tid = threadIdx.x, lane = tid & 63, w = tid >> 6;
  int wn2 = w * 32;  // wave owns 32 n-cols (one GN group); full 64 m-rows
  int lr = lane & 15, lk = lane >> 4;
  size_t aBase = (size_t)(b * 2048 + m0);
  const u16* Bb = KtVTh + ((size_t)b << 20);

  stageA2(Qh, aBase, 1024, 0, sA0, w, lane);
  stage4(Bb, (size_t)n0, 1024, 0, sB0, w, lane);
  const int NT = 16;  // K=1024
  for (int t = 0; t < NT; ++t) {
    u16* cA = (t & 1) ? sA1 : sA0;
    u16* cB = (t & 1) ? sB1 : sB0;
    if (t + 1 < NT) {
      u16* nA = (t & 1) ? sA0 : sA1;
      u16* nB = (t & 1) ? sB0 : sB1;
      stageA2(Qh, aBase, 1024, (t + 1) << 6, nA, w, lane);
      stage4(Bb, (size_t)n0, 1024, (t + 1) << 6, nB, w, lane);
      asm volatile("s_waitcnt vmcnt(6)" ::: "memory");
    } else {
      asm volatile("s_waitcnt vmcnt(0)" ::: "memory");
    }
    __builtin_amdgcn_s_barrier();
    __builtin_amdgcn_sched_barrier(0);
    bfx8 a[8], bfr[4];
#pragma unroll
    for (int h = 0; h < 2; ++h) {
#pragma unroll
      for (int i = 0; i < 4; ++i) a[h * 4 + i] = ldsw(cA, i * 16 + lr, h * 4 + lk);
#pragma unroll
      for (int j = 0; j < 2; ++j) bfr[h * 2 + j] = ldsw(cB, wn2 + j * 16 + lr, h * 4 + lk);
    }
    asm volatile("s_waitcnt lgkmcnt(0)" ::: "memory");
    __builtin_amdgcn_sched_barrier(0);
    __builtin_amdgcn_s_barrier();
#pragma unroll
    for (int h = 0; h < 2; ++h)
#pragma unroll
      for (int mi = 0; mi < 4; ++mi)
#pragma unroll
        for (int ni = 0; ni < 2; ++ni)
          acc[mi][ni] = mfma16(a[h * 4 + mi], bfr[h * 2 + ni], acc[mi][ni]);
  }

  // GroupNorm epilogue: per row m, the wave's group values are acc[mi][0/1][r] across
  // 16 lr lanes (32 channels). Two-pass mean/var via shfl_xor masks 1,2,4,8.
  float wv[2], bvv[2];
#pragma unroll
  for (int ni = 0; ni < 2; ++ni) {
    int n = n0 + wn2 + ni * 16 + lr;
    wv[ni] = gw[n];
    bvv[ni] = gb[n];
  }
#pragma unroll
  for (int mi = 0; mi < 4; ++mi) {
    fx4 o0, o1;
#pragma unroll
    for (int r = 0; r < 4; ++r) {
      float v0 = acc[mi][0][r], v1 = acc[mi][1][r];
      float s = v0 + v1;
#pragma unroll
      for (int mk = 1; mk <= 8; mk <<= 1) s += __shfl_xor(s, mk);
      float mean = s * (1.f / 32.f);
      float d = (v0 - mean) * (v0 - mean) + (v1 - mean) * (v1 - mean);
#pragma unroll
      for (int mk = 1; mk <= 8; mk <<= 1) d += __shfl_xor(d, mk);
      float rstd = rsqrtf(d * (1.f / 32.f) + 1e-5f);
      o0[r] = (v0 - mean) * rstd * wv[0] + bvv[0];
      o1[r] = (v1 - mean) * rstd * wv[1] + bvv[1];
    }
    int mbase = m0 + mi * 16 + lk * 4;  // t index within batch, 16B-aligned
#pragma unroll
    for (int ni = 0; ni < 2; ++ni) {
      int n = n0 + wn2 + ni * 16 + lr;
      fx4 ov = ni ? o1 : o0;
      *reinterpret_cast<fx4*>(out + (((size_t)(b << 10) + n) << 11) + mbase) = ov;
    }
  }
}

extern "C" void kernel_launch(void* const* d_in, const int* in_sizes, int n_in,
                              void* d_out, int out_size, void* d_ws, size_t ws_size,
                              hipStream_t stream) {
  const float* x = (const float*)d_in[0];
  const float* W = (const float*)d_in[1];
  const float* b_in = (const float*)d_in[2];
  const float* gnw = (const float*)d_in[3];
  const float* gnb = (const float*)d_in[4];
  float* out = (float*)d_out;
  char* ws = (char*)d_ws;

  // Workspace (bytes): xh@0(16M) WTh@16M(6M) Qh@22M(16M) Kth@38M(16M) Vth@54M(16M)
  // KtVTh@70M(8M) tabTI@78M(8M) tabIT@86M(8M). Total ~94MB.
  u16* xh = (u16*)(ws + 0);
  u16* WTh = (u16*)(ws + 16777216);
  u16* Qh = (u16*)(ws + 23068672);
  u16* Kth = (u16*)(ws + 39845888);
  u16* Vth = (u16*)(ws + 56623104);
  u16* KtVTh = (u16*)(ws + 73400320);
  float2* tabTI = (float2*)(ws + 81788928);
  float2* tabIT = (float2*)(ws + 90177536);

  k_prep<<<15360, 256, 0, stream>>>(x, W, xh, WTh, tabTI, tabIT);
  k_gemm1f<<<1536, 256, 0, stream>>>(xh, WTh, b_in, tabTI, tabIT, Qh, Kth, Vth);
  k_gemm2<<<512, 256, 0, stream>>>(Kth, Vth, KtVTh);
  k_gemm3g<<<1024, 256, 0, stream>>>(Qh, KtVTh, gnw, gnb, out);
}

// Round 15
// 133.713 us; speedup vs baseline: 1.0601x; 1.0601x over previous
//
#include <hip/hip_runtime.h>

// ActivatedAttention: out = transpose(GroupNorm( relu(rope(Q)) @ [relu(rope(K))^T @ relu(V)] )).
// B=4, T=2048, D=1024. y = Q @ (K^T V)  (no softmax -> associativity).
// All GEMMs hi-only bf16 (absmax 0.0234 vs threshold 0.0728, bench-validated).
//  - gemm1f (r15): r10 structure + B PREFETCH-2 (B triple-buffered, issued 2 K-steps
//    ahead; A dbuf). 80KB staging still 2 blocks/CU. Wait: vmcnt(12) mid / 8 / 0.
//  - gemm2: r12 64x128 tile, 512 blocks (K=2048 -> long loop amortizes).
//  - gemm3g: r13 128x128, 512 blocks (r14 lesson: 64x128 pays only for long K;
//    K=1024 doubled fixed costs + B re-reads -> -9us).
// Barrier skeleton (r7-proven): vmcnt(N); s_barrier; sched_barrier; ds_reads;
// lgkmcnt(0); sched_barrier; s_barrier; MFMAs.
// r11: BK=32 doubles per-sync overhead. r9: 32x32 MFMA frags bank-conflict on 128B rows.
// r12: in-kernel f32 A staging thrashes L2. Staging swizzle: linear LDS dest,
// XOR-swizzled global source + swizzled ds_read (slot ^= row&7) -> conflict-free.

typedef unsigned short u16;
typedef __attribute__((ext_vector_type(8))) unsigned short u16x8;
typedef __attribute__((ext_vector_type(4))) float fx4;
typedef __attribute__((ext_vector_type(8))) __bf16 bfx8;

#define TP 129  // epilogue f32 tile pitch

__device__ __forceinline__ u16 f2bh(float v) {  // f32 -> bf16 RNE
  unsigned u = __float_as_uint(v);
  return (u16)((u + 0x7FFFu + ((u >> 16) & 1u)) >> 16);
}
__device__ __forceinline__ fx4 mfma16(bfx8 a, bfx8 b, fx4 c) {
  return __builtin_amdgcn_mfma_f32_16x16x32_bf16(a, b, c, 0, 0, 0);
}

__device__ __forceinline__ void gload16(const u16* g, u16* l) {
  __builtin_amdgcn_global_load_lds(
      (const __attribute__((address_space(1))) unsigned int*)(const void*)g,
      (__attribute__((address_space(3))) unsigned int*)(void*)l, 16, 0, 0);
}

// Swizzled LDS read: buffer is [rows][8 slots of 16B]; logical slot q of row r
// lives at physical slot q ^ (r&7).
__device__ __forceinline__ bfx8 ldsw(const u16* lds, int row, int slot) {
  const char* p = (const char*)lds + row * 128 + ((slot ^ (row & 7)) << 4);
  return __builtin_bit_cast(bfx8, *reinterpret_cast<const u16x8*>(p));
}

// Stage 128 rows x 64 cols (4 chunks/thread) via global_load_lds.
__device__ __forceinline__ void stage4(const u16* __restrict__ A,
                                       size_t rowBase, int stride, int k0,
                                       u16* lds, int w, int lane) {
#pragma unroll
  for (int i = 0; i < 4; ++i) {
    int c = ((w * 4 + i) << 6) + lane;
    int r = c >> 3, s = c & 7;
    int t = s ^ (r & 7);
    const u16* src = A + (rowBase + (size_t)r) * (size_t)stride + k0 + (t << 3);
    gload16(src, lds + ((w * 4 + i) << 9));
  }
}

// Stage 64 rows x 64 cols (2 chunks/thread) via global_load_lds.
__device__ __forceinline__ void stageA2(const u16* __restrict__ A,
                                        size_t rowBase, int stride, int k0,
                                        u16* lds, int w, int lane) {
#pragma unroll
  for (int i = 0; i < 2; ++i) {
    int c = ((w * 2 + i) << 6) + lane;  // 0..511
    int r = c >> 3, s = c & 7;
    int t = s ^ (r & 7);
    const u16* src = A + (rowBase + (size_t)r) * (size_t)stride + k0 + (t << 3);
    gload16(src, lds + ((w * 2 + i) << 9));
  }
}

// ---- Pipelined hi-only 128x128 GEMM core, BK=64, dbuf staging (r10-proven).
__device__ inline void gemm_core_pipe(const u16* __restrict__ A, size_t aBase, int aStr,
                                      const u16* __restrict__ B, size_t bBase, int bStr, int K,
                                      u16* sA0, u16* sB0, u16* sA1, u16* sB1,
                                      fx4 acc[4][4], int w, int lane) {
  int wm = (w >> 1) * 64, wn = (w & 1) * 64;
  int lr = lane & 15, lk = lane >> 4;
  stage4(A, aBase, aStr, 0, sA0, w, lane);
  stage4(B, bBase, bStr, 0, sB0, w, lane);
  int NT = K >> 6;
  for (int t = 0; t < NT; ++t) {
    u16* cA = (t & 1) ? sA1 : sA0;
    u16* cB = (t & 1) ? sB1 : sB0;
    if (t + 1 < NT) {
      u16* nA = (t & 1) ? sA0 : sA1;
      u16* nB = (t & 1) ? sB0 : sB1;
      stage4(A, aBase, aStr, (t + 1) << 6, nA, w, lane);
      stage4(B, bBase, bStr, (t + 1) << 6, nB, w, lane);
      asm volatile("s_waitcnt vmcnt(8)" ::: "memory");  // tile-t loads done, 8 in flight
    } else {
      asm volatile("s_waitcnt vmcnt(0)" ::: "memory");
    }
    __builtin_amdgcn_s_barrier();       // tile t resident (all waves)
    __builtin_amdgcn_sched_barrier(0);  // do NOT hoist reads above the barrier (race!)
    bfx8 a[8], b[8];
#pragma unroll
    for (int h = 0; h < 2; ++h)
#pragma unroll
      for (int i = 0; i < 4; ++i) {
        a[h * 4 + i] = ldsw(cA, wm + i * 16 + lr, h * 4 + lk);
        b[h * 4 + i] = ldsw(cB, wn + i * 16 + lr, h * 4 + lk);
      }
    asm volatile("s_waitcnt lgkmcnt(0)" ::: "memory");  // reads landed in regs
    __builtin_amdgcn_sched_barrier(0);
    __builtin_amdgcn_s_barrier();       // WAR: buffers free; MFMAs overlap next staging
#pragma unroll
    for (int h = 0; h < 2; ++h)
#pragma unroll
      for (int mi = 0; mi < 4; ++mi)
#pragma unroll
        for (int ni = 0; ni < 4; ++ni)
          acc[mi][ni] = mfma16(a[h * 4 + mi], b[h * 4 + ni], acc[mi][ni]);
  }
}

// ---- K0: merged prep: castX (blocks 0..4095), transW (4096..7167), ropetab (7168..15359)
__global__ void k_prep(const float* __restrict__ x, const float* __restrict__ W,
                       u16* __restrict__ xh, u16* __restrict__ WTh,
                       float2* __restrict__ tabTI, float2* __restrict__ tabIT) {
  __shared__ float tile[32][33];
  int bid = blockIdx.x, tid = threadIdx.x;
  if (bid < 4096) {  // cast x -> bf16, 8 elems/thread
    size_t i = ((size_t)bid * 256 + tid) * 8;
    fx4 v0 = *reinterpret_cast<const fx4*>(x + i);
    fx4 v1 = *reinterpret_cast<const fx4*>(x + i + 4);
    u16x8 h;
#pragma unroll
    for (int j = 0; j < 4; ++j) {
      h[j] = f2bh(v0[j]);
      h[4 + j] = f2bh(v1[j]);
    }
    *reinterpret_cast<u16x8*>(xh + i) = h;
  } else if (bid < 7168) {  // transpose W -> WT[3072][1024] bf16
    int idx = bid - 4096;
    int n0 = (idx % 96) * 32, k0 = (idx / 96) * 32;
    int c = tid & 31, r4 = tid >> 5;
#pragma unroll
    for (int it = 0; it < 4; ++it) {
      int r = r4 + it * 8;
      tile[r][c] = W[(size_t)(k0 + r) * 3072 + n0 + c];
    }
    __syncthreads();
#pragma unroll
    for (int it = 0; it < 4; ++it) {
      int r = r4 + it * 8;
      WTh[(size_t)(n0 + r) * 1024 + k0 + c] = f2bh(tile[c][r]);
    }
  } else {  // rope tables: float2(cos,sin)
    int half = (bid - 7168) >> 12;  // 0: tabTI, 1: tabIT
    int idx = ((bid - 7168) & 4095) * 256 + tid;
    int t, i;
    if (half == 0) {
      t = idx >> 9;
      i = idx & 511;
    } else {
      i = idx >> 11;
      t = idx & 2047;
    }
    float invf = exp2f(-(float)i * (13.287712379549449f / 512.f));  // 10000^(-i/512)
    float ang = (float)t * invf, s, c;
    sincosf(ang, &s, &c);
    if (half == 0)
      tabTI[idx] = make_float2(c, s);
    else
      tabIT[idx] = make_float2(c, s);
  }
}

// ---- G1 fused: relu(rope(x@W+b)) -> Qh row-major, Kth/Vth transposed [B][D][T].
// B prefetch-2 (triple-buffered B), A dbuf. 80KB staging aliased with 66KB epilogue tile.
__global__ __launch_bounds__(256) void k_gemm1f(const u16* __restrict__ xh,
                                                const u16* __restrict__ WTh,
                                                const float* __restrict__ b_in,
                                                const float2* __restrict__ tabTI,
                                                const float2* __restrict__ tabIT,
                                                u16* __restrict__ Qh, u16* __restrict__ Kth,
                                                u16* __restrict__ Vth) {
  __shared__ __align__(16) char smembuf[81920];  // 80KB -> still 2 blocks/CU
  float* shbuf = (float*)smembuf;                // epilogue f32 tile (66KB) aliases front
  u16* sA0 = (u16*)smembuf;
  u16* sA1 = sA0 + 128 * 64;
  u16* sB0 = sA1 + 128 * 64;
  u16* sB1 = sB0 + 128 * 64;
  u16* sB2 = sB1 + 128 * 64;
  // XCD-chunked swizzle: 1536 blocks = 8 XCD x (8 mt x 24 nt), mt-fastest within chunk.
  int bid = blockIdx.x;
  int xcd = bid & 7, idx = bid >> 3;
  int mt = (xcd << 3) + (idx & 7), nt = idx >> 3;
  int m0 = mt << 7, n0 = nt << 7;
  int tid = threadIdx.x, lane = tid & 63, w = tid >> 6;
  int wm = (w >> 1) * 64, wn = (w & 1) * 64;
  int lr = lane & 15, lk = lane >> 4;
  fx4 acc[4][4];
#pragma unroll
  for (int i = 0; i < 4; ++i)
#pragma unroll
    for (int j = 0; j < 4; ++j) acc[i][j] = fx4{0.f, 0.f, 0.f, 0.f};

  // Prologue: A(0), B(0), B(1) -> 12 outstanding.
  stage4(xh, (size_t)m0, 1024, 0, sA0, w, lane);
  stage4(WTh, (size_t)n0, 1024, 0, sB0, w, lane);
  stage4(WTh, (size_t)n0, 1024, 64, sB1, w, lane);
  const int NT = 16;
  for (int t = 0; t < NT; ++t) {
    u16* cA = (t & 1) ? sA1 : sA0;
    int bm = t % 3;
    u16* cB = (bm == 0) ? sB0 : (bm == 1) ? sB1 : sB2;
    // Queue order: B(t) < A(t) < B(t+1) < A(t+1) < B(t+2). Drain through A(t):
    if (t + 2 < NT) {
      u16* nA = (t & 1) ? sA0 : sA1;
      int b2 = (t + 2) % 3;
      u16* nB = (b2 == 0) ? sB0 : (b2 == 1) ? sB1 : sB2;
      stage4(xh, (size_t)m0, 1024, (t + 1) << 6, nA, w, lane);
      stage4(WTh, (size_t)n0, 1024, (t + 2) << 6, nB, w, lane);
      asm volatile("s_waitcnt vmcnt(12)" ::: "memory");  // B(t+1),A(t+1),B(t+2) in flight
    } else if (t + 1 < NT) {
      u16* nA = (t & 1) ? sA0 : sA1;
      stage4(xh, (size_t)m0, 1024, (t + 1) << 6, nA, w, lane);
      asm volatile("s_waitcnt vmcnt(8)" ::: "memory");   // B(NT-1),A(NT-1) in flight
    } else {
      asm volatile("s_waitcnt vmcnt(0)" ::: "memory");
    }
    __builtin_amdgcn_s_barrier();       // tile t resident (all waves)
    __builtin_amdgcn_sched_barrier(0);  // do NOT hoist reads above the barrier (race!)
    bfx8 a[8], b[8];
#pragma unroll
    for (int h = 0; h < 2; ++h)
#pragma unroll
      for (int i = 0; i < 4; ++i) {
        a[h * 4 + i] = ldsw(cA, wm + i * 16 + lr, h * 4 + lk);
        b[h * 4 + i] = ldsw(cB, wn + i * 16 + lr, h * 4 + lk);
      }
    asm volatile("s_waitcnt lgkmcnt(0)" ::: "memory");
    __builtin_amdgcn_sched_barrier(0);
    __builtin_amdgcn_s_barrier();       // WAR: buffers free; MFMAs overlap next staging
#pragma unroll
    for (int h = 0; h < 2; ++h)
#pragma unroll
      for (int mi = 0; mi < 4; ++mi)
#pragma unroll
        for (int ni = 0; ni < 4; ++ni)
          acc[mi][ni] = mfma16(a[h * 4 + mi], b[h * 4 + ni], acc[mi][ni]);
  }

  // ---- Epilogue: acc+bias -> f32 LDS tile [n_local][m_local], then store in output
  // order with vectorized u16x8 stores + table-based rope.
  float bv[4];
#pragma unroll
  for (int ni = 0; ni < 4; ++ni) bv[ni] = b_in[n0 + wn + ni * 16 + lr];
  __syncthreads();  // all LDS reads of staging done before overwrite
#pragma unroll
  for (int mi = 0; mi < 4; ++mi)
#pragma unroll
    for (int ni = 0; ni < 4; ++ni)
#pragma unroll
      for (int r = 0; r < 4; ++r)
        shbuf[(wn + ni * 16 + lr) * TP + wm + mi * 16 + lk * 4 + r] = acc[mi][ni][r] + bv[ni];
  __syncthreads();

  int part = n0 >> 10;       // 0=Q, 1=K, 2=V (uniform per block)
  int d0 = n0 - (part << 10);
  int bb = m0 >> 11, tb = m0 & 2047;  // 128-row tiles never cross batch boundary
  int rl0 = tid >> 4;        // row within tile (per pass: +16)
  int cc = (tid & 15) * 8;   // 8-elem column chunk

  if (part == 2) {           // V: relu only, store [d][t]
#pragma unroll
    for (int pass = 0; pass < 8; ++pass) {
      int rl = rl0 + pass * 16;
      u16x8 o;
#pragma unroll
      for (int j = 0; j < 8; ++j) o[j] = f2bh(fmaxf(shbuf[rl * TP + cc + j], 0.f));
      *reinterpret_cast<u16x8*>(Vth + (((size_t)(bb << 10) + d0 + rl) << 11) + tb + cc) = o;
    }
  } else if (part == 1) {    // K: rope (rows d, d^1) + relu, store [d][t]
#pragma unroll
    for (int pass = 0; pass < 8; ++pass) {
      int rl = rl0 + pass * 16;
      int d = d0 + rl;
      const float2* tp = tabIT + ((size_t)(d >> 1) << 11) + tb + cc;
      const float* e = shbuf + (rl & ~1) * TP + cc;   // even row
      const float* oo = shbuf + (rl | 1) * TP + cc;   // odd row
      int isOdd = d & 1;
      u16x8 o;
#pragma unroll
      for (int j = 0; j < 8; ++j) {
        float2 cs = tp[j];
        float x1 = e[j], x2 = oo[j];
        float v = isOdd ? (x1 * cs.y + x2 * cs.x) : (x1 * cs.x - x2 * cs.y);
        o[j] = f2bh(fmaxf(v, 0.f));
      }
      *reinterpret_cast<u16x8*>(Kth + (((size_t)(bb << 10) + d) << 11) + tb + cc) = o;
    }
  } else {                   // Q: rope along d, store [m][d]
#pragma unroll
    for (int pass = 0; pass < 8; ++pass) {
      int rl = rl0 + pass * 16;  // m_local
      int m = m0 + rl, t = m & 2047;
      const float2* tp = tabTI + ((size_t)t << 9) + ((d0 + cc) >> 1);
      u16x8 o;
#pragma unroll
      for (int jp = 0; jp < 4; ++jp) {
        float x1 = shbuf[(cc + 2 * jp) * TP + rl];
        float x2 = shbuf[(cc + 2 * jp + 1) * TP + rl];
        float2 cs = tp[jp];
        o[2 * jp] = f2bh(fmaxf(x1 * cs.x - x2 * cs.y, 0.f));
        o[2 * jp + 1] = f2bh(fmaxf(x1 * cs.y + x2 * cs.x, 0.f));
      }
      *reinterpret_cast<u16x8*>(Qh + ((size_t)m << 10) + d0 + cc) = o;
    }
  }
}

// ---- G2: KtVT[b][n][m] = (K^T V)[m][n], bf16 out. 64x128 tile, 512 blocks (r12-proven).
__global__ __launch_bounds__(256) void k_gemm2(const u16* __restrict__ Kth, const u16* __restrict__ Vth,
                                               u16* __restrict__ KtVTh) {
  __shared__ u16 smem[2 * (64 + 128) * 64];  // 48KB
  u16* sA0 = smem;
  u16* sB0 = sA0 + 64 * 64;
  u16* sA1 = sB0 + 128 * 64;
  u16* sB1 = sA1 + 64 * 64;
  fx4 acc[4][2];
#pragma unroll
  for (int i = 0; i < 4; ++i)
#pragma unroll
    for (int j = 0; j < 2; ++j) acc[i][j] = fx4{0.f, 0.f, 0.f, 0.f};
  // XCD swizzle: xcd owns (b = xcd>>1, 8 mt x 8 nt), mt-fastest -> A slice 2MB resident.
  int bid = blockIdx.x;
  int xcd = bid & 7, idx = bid >> 3;  // idx 0..63
  int b = xcd >> 1;
  int mt = (xcd & 1) * 8 + (idx & 7), nt = idx >> 3;
  int m0 = mt << 6, n0 = nt << 7;
  int tid = threadIdx.x, lane = tid & 63, w = tid >> 6;
  int wn2 = w * 32;  // wave owns 32 n-cols; full 64 m-rows
  int lr = lane & 15, lk = lane >> 4;
  const u16* Ab = Kth + ((size_t)b << 21);
  const u16* Bb = Vth + ((size_t)b << 21);

  stageA2(Ab, (size_t)m0, 2048, 0, sA0, w, lane);
  stage4(Bb, (size_t)n0, 2048, 0, sB0, w, lane);
  const int NT = 32;  // K=2048
  for (int t = 0; t < NT; ++t) {
    u16* cA = (t & 1) ? sA1 : sA0;
    u16* cB = (t & 1) ? sB1 : sB0;
    if (t + 1 < NT) {
      u16* nA = (t & 1) ? sA0 : sA1;
      u16* nB = (t & 1) ? sB0 : sB1;
      stageA2(Ab, (size_t)m0, 2048, (t + 1) << 6, nA, w, lane);
      stage4(Bb, (size_t)n0, 2048, (t + 1) << 6, nB, w, lane);
      asm volatile("s_waitcnt vmcnt(6)" ::: "memory");
    } else {
      asm volatile("s_waitcnt vmcnt(0)" ::: "memory");
    }
    __builtin_amdgcn_s_barrier();
    __builtin_amdgcn_sched_barrier(0);
    bfx8 a[8], bfr[4];
#pragma unroll
    for (int h = 0; h < 2; ++h) {
#pragma unroll
      for (int i = 0; i < 4; ++i) a[h * 4 + i] = ldsw(cA, i * 16 + lr, h * 4 + lk);
#pragma unroll
      for (int j = 0; j < 2; ++j) bfr[h * 2 + j] = ldsw(cB, wn2 + j * 16 + lr, h * 4 + lk);
    }
    asm volatile("s_waitcnt lgkmcnt(0)" ::: "memory");
    __builtin_amdgcn_sched_barrier(0);
    __builtin_amdgcn_s_barrier();
#pragma unroll
    for (int h = 0; h < 2; ++h)
#pragma unroll
      for (int mi = 0; mi < 4; ++mi)
#pragma unroll
        for (int ni = 0; ni < 2; ++ni)
          acc[mi][ni] = mfma16(a[h * 4 + mi], bfr[h * 2 + ni], acc[mi][ni]);
  }
#pragma unroll
  for (int mi = 0; mi < 4; ++mi)
#pragma unroll
    for (int ni = 0; ni < 2; ++ni)
#pragma unroll
      for (int r = 0; r < 4; ++r) {
        int m = m0 + mi * 16 + lk * 4 + r;
        int n = n0 + wn2 + ni * 16 + lr;
        KtVTh[((size_t)b << 20) + ((size_t)n << 10) + m] = f2bh(acc[mi][ni][r]);
      }
}

// ---- G3 fused (r13-proven): y = Q @ KtV + GroupNorm + transposed store out[b][d][t].
// 128x128 tile, 512 blocks, 2 XCDs per batch.
__global__ __launch_bounds__(256) void k_gemm3g(const u16* __restrict__ Qh, const u16* __restrict__ KtVTh,
                                                const float* __restrict__ gw, const float* __restrict__ gb,
                                                float* __restrict__ out) {
  __shared__ u16 smem[4 * 128 * 64];
  u16* sA0 = smem;
  u16* sB0 = sA0 + 128 * 64;
  u16* sA1 = sB0 + 128 * 64;
  u16* sB1 = sA1 + 128 * 64;
  fx4 acc[4][4];
#pragma unroll
  for (int i = 0; i < 4; ++i)
#pragma unroll
    for (int j = 0; j < 4; ++j) acc[i][j] = fx4{0.f, 0.f, 0.f, 0.f};
  int bid = blockIdx.x;
  int xcd = bid & 7, idx = bid >> 3;  // idx 0..63
  int b = xcd >> 1;
  int mt = (xcd & 1) * 8 + (idx & 7), nt = idx >> 3;
  int m0 = mt << 7, n0 = nt << 7;
  int tid = threadIdx.x, lane = tid & 63, w = tid >> 6;
  gemm_core_pipe(Qh, (size_t)(b * 2048 + m0), 1024, KtVTh + ((size_t)b << 20), (size_t)n0, 1024,
                 1024, sA0, sB0, sA1, sB1, acc, w, lane);
  int wm = (w >> 1) * 64, wn = (w & 1) * 64, lr = lane & 15, lk = lane >> 4;
  float wv[4], bvv[4];
#pragma unroll
  for (int ni = 0; ni < 4; ++ni) {
    int n = n0 + wn + ni * 16 + lr;
    wv[ni] = gw[n];
    bvv[ni] = gb[n];
  }
#pragma unroll
  for (int mi = 0; mi < 4; ++mi) {
    fx4 o0, o1, o2, o3;
#pragma unroll
    for (int r = 0; r < 4; ++r) {
      float v0 = acc[mi][0][r], v1 = acc[mi][1][r], v2 = acc[mi][2][r], v3 = acc[mi][3][r];
      float sA2 = v0 + v1, sB2 = v2 + v3;
#pragma unroll
      for (int mk = 1; mk <= 8; mk <<= 1) {
        sA2 += __shfl_xor(sA2, mk);
        sB2 += __shfl_xor(sB2, mk);
      }
      float mA = sA2 * (1.f / 32.f), mB = sB2 * (1.f / 32.f);
      float dA = (v0 - mA) * (v0 - mA) + (v1 - mA) * (v1 - mA);
      float dB = (v2 - mB) * (v2 - mB) + (v3 - mB) * (v3 - mB);
#pragma unroll
      for (int mk = 1; mk <= 8; mk <<= 1) {
        dA += __shfl_xor(dA, mk);
        dB += __shfl_xor(dB, mk);
      }
      float rA = rsqrtf(dA * (1.f / 32.f) + 1e-5f);
      float rB = rsqrtf(dB * (1.f / 32.f) + 1e-5f);
      o0[r] = (v0 - mA) * rA * wv[0] + bvv[0];
      o1[r] = (v1 - mA) * rA * wv[1] + bvv[1];
      o2[r] = (v2 - mB) * rB * wv[2] + bvv[2];
      o3[r] = (v3 - mB) * rB * wv[3] + bvv[3];
    }
    int mbase = m0 + wm + mi * 16 + lk * 4;  // t index, 16B-aligned
#pragma unroll
    for (int ni = 0; ni < 4; ++ni) {
      int n = n0 + wn + ni * 16 + lr;
      fx4 ov = (ni == 0) ? o0 : (ni == 1) ? o1 : (ni == 2) ? o2 : o3;
      *reinterpret_cast<fx4*>(out + (((size_t)(b << 10) + n) << 11) + mbase) = ov;
    }
  }
}

extern "C" void kernel_launch(void* const* d_in, const int* in_sizes, int n_in,
                              void* d_out, int out_size, void* d_ws, size_t ws_size,
                              hipStream_t stream) {
  const float* x = (const float*)d_in[0];
  const float* W = (const float*)d_in[1];
  const float* b_in = (const float*)d_in[2];
  const float* gnw = (const float*)d_in[3];
  const float* gnb = (const float*)d_in[4];
  float* out = (float*)d_out;
  char* ws = (char*)d_ws;

  // Workspace (bytes): xh@0(16M) WTh@16M(6M) Qh@22M(16M) Kth@38M(16M) Vth@54M(16M)
  // KtVTh@70M(8M) tabTI@78M(8M) tabIT@86M(8M). Total ~94MB.
  u16* xh = (u16*)(ws + 0);
  u16* WTh = (u16*)(ws + 16777216);
  u16* Qh = (u16*)(ws + 23068672);
  u16* Kth = (u16*)(ws + 39845888);
  u16* Vth = (u16*)(ws + 56623104);
  u16* KtVTh = (u16*)(ws + 73400320);
  float2* tabTI = (float2*)(ws + 81788928);
  float2* tabIT = (float2*)(ws + 90177536);

  k_prep<<<15360, 256, 0, stream>>>(x, W, xh, WTh, tabTI, tabIT);
  k_gemm1f<<<1536, 256, 0, stream>>>(xh, WTh, b_in, tabTI, tabIT, Qh, Kth, Vth);
  k_gemm2<<<512, 256, 0, stream>>>(Kth, Vth, KtVTh);
  k_gemm3g<<<512, 256, 0, stream>>>(Qh, KtVTh, gnw, gnb, out);
}